// Round 17
// baseline (191.994 us; speedup 1.0000x reference)
//
#include <hip/hip_runtime.h>
#include <stdint.h>
#include <math.h>

typedef __attribute__((ext_vector_type(8))) short short8;
typedef __attribute__((ext_vector_type(4))) float f32x4;
typedef __attribute__((ext_vector_type(4))) unsigned short ushort4v;

#define DEV static __device__ __forceinline__

DEV unsigned short f2bf(float f) {
    unsigned int u = __float_as_uint(f);
    u += 0x7fffu + ((u >> 16) & 1u);
    return (unsigned short)(u >> 16);
}
DEV float bf2f(unsigned short h) { return __uint_as_float(((unsigned int)h) << 16); }
// pack trunc-bf16(a) low, trunc-bf16(b) high — single v_perm_b32
DEV unsigned int pkP(float a, float b) {
    return __builtin_amdgcn_perm(__float_as_uint(b), __float_as_uint(a), 0x07060302u);
}

#define GLDS16(g, l)                                                                     \
    __builtin_amdgcn_global_load_lds((const __attribute__((address_space(1))) void*)(g), \
                                     (__attribute__((address_space(3))) void*)(l), 16, 0, 0)

// ---------------- workspace layout (bytes) ----------------
static const size_t OFF_XB   = 0;                       // X bf16 [8192][512]
static const size_t OFF_YB   = 8388608;                 // Y bf16
static const size_t OFF_WCXT = 16777216;                // WcatX^T bf16 [3072][512]
static const size_t OFF_WCYT = 19922944;                // WcatY^T
static const size_t OFF_WXT  = 23068672;                // W_X^T bf16 [512][1024]
static const size_t OFF_WYT  = 24117248;                // W_Y^T
static const size_t OFF_BX   = 25165824;                // biasX f32 [3072]
static const size_t OFF_BY   = 25178112;                // biasY f32 [3072]
static const size_t OFF_PX   = 25190400;                // PX bf16 [8192][3072]
static const size_t OFF_PY   = 75522048;                // PY bf16
static const size_t OFF_VT0  = 125853696;               // VT_xx bf16 [8][512][1024]
static const size_t OFF_VT1  = 134242304;               // VT_xy
static const size_t OFF_VT2  = 142630912;               // VT_yx
static const size_t OFF_VT3  = 151019520;               // VT_yy
static const size_t OFF_OX   = 159408128;               // Ocat_x bf16 [8192][1024]
static const size_t OFF_OY   = 176185344;               // Ocat_y

// ---------------- pack + cast (merged) ----------------
struct PackA {
    const float* w[12];
    const float* b[12];
    const float* wox;   // W_X [1024][512]
    const float* woy;   // W_Y
    const float* X;
    const float* Y;
};

// z in [0,12): Wcat pack (K-branches z in {1,4,6,10} pre-scaled by
// cs = log2(e)/sqrt(512) so QK^T emerges in log2 units -> softmax = raw exp2).
// z in {12,13}: W_X / W_Y transpose-pack.  z in [14,30): X/Y f32->bf16 cast.
__global__ __launch_bounds__(256) void k_pack(PackA p, unsigned short* WcatXT,
                                              unsigned short* WcatYT, float* biasX, float* biasY,
                                              unsigned short* WXT, unsigned short* WYT,
                                              unsigned short* Xb, unsigned short* Yb) {
    int z = blockIdx.z;
    __shared__ float tile[32][33];
    int tx = threadIdx.x, ty = threadIdx.y;
    if (z >= 14) {
        int flat = (blockIdx.y * 16 + blockIdx.x) * 256 + ty * 32 + tx;
        int q = (z - 14) * 131072 + flat;  // float4 index over X then Y
        const int NE = 1048576;
        const float* s;
        unsigned short* d;
        if (q < NE) { s = p.X; d = Xb; } else { s = p.Y; d = Yb; q -= NE; }
        float4 v = ((const float4*)s)[q];
        ushort4v o = {f2bf(v.x), f2bf(v.y), f2bf(v.z), f2bf(v.w)};
        ((ushort4v*)d)[q] = o;
        return;
    }
    if (z < 12) {
        if (blockIdx.y >= 16) return;
        const float sc = (z == 1 || z == 4 || z == 6 || z == 10) ? 0.0637587160f : 1.0f;
        const float* src = p.w[z];
        unsigned short* dst = (z < 6) ? (WcatXT + z * 262144) : (WcatYT + (z - 6) * 262144);
        int x = blockIdx.x * 32 + tx;
        int y0 = blockIdx.y * 32 + ty;
#pragma unroll
        for (int j = 0; j < 4; j++) tile[ty + j * 8][tx] = src[(y0 + j * 8) * 512 + x];
        __syncthreads();
        int x2 = blockIdx.y * 32 + tx;
        int y2 = blockIdx.x * 32 + ty;
#pragma unroll
        for (int j = 0; j < 4; j++)
            dst[(y2 + j * 8) * 512 + x2] = f2bf(sc * tile[tx][ty + j * 8]);
        if (blockIdx.x == 0 && blockIdx.y == 0) {
            int t = ty * 32 + tx;
            float* bd = (z < 6) ? (biasX + z * 512) : (biasY + (z - 6) * 512);
            bd[t] = sc * p.b[z][t];
            bd[t + 256] = sc * p.b[z][t + 256];
        }
    } else {
        const float* src = (z == 13) ? p.woy : p.wox;       // [1024][512]
        unsigned short* dst = (z == 13) ? WYT : WXT;        // [512][1024]
        int x = blockIdx.x * 32 + tx;                       // src col 0..511
        int y0 = blockIdx.y * 32 + ty;                      // src row 0..1023
#pragma unroll
        for (int j = 0; j < 4; j++) tile[ty + j * 8][tx] = src[(y0 + j * 8) * 512 + x];
        __syncthreads();
        int x2 = blockIdx.y * 32 + tx;
        int y2 = blockIdx.x * 32 + ty;
#pragma unroll
        for (int j = 0; j < 4; j++) dst[(y2 + j * 8) * 1024 + x2] = f2bf(tile[tx][ty + j * 8]);
    }
}

// ---------------- projection GEMM (counted-vmcnt + 2-sub-phase K-step) ----------------
// C[8192][3072] = A[8192][512] @ BT[3072][512]^T + bias, bf16 out.
// BM=256, BN=128, BK=32; 512 threads = 8 waves; 3 LDS buffers rotate; tile T+2
// staged while computing T; s_waitcnt vmcnt(3) + raw s_barrier per K-tile.
// K-step split into 2 sub-phases (8 MFMA each) with a mid s_barrier + setprio:
// wave role-split lets lagging waves' ds_reads overlap leading waves' MFMAs.
// XCD-chunked grid swizzle: XCD k owns m-panels {4k..4k+3} x all n (A+B fit L2).
// Epilogue: per-wave 64x64 tile staged in LDS, then 8 dwordx4 stores/thread.
struct ProjArgs {
    const unsigned short* A[2];
    const unsigned short* BT[2];
    const float* bias[2];
    unsigned short* C[2];
    unsigned short* vtA[2];
    unsigned short* vtB[2];
    int svA[2], svB[2];
};

__global__ __launch_bounds__(512) void k_proj(ProjArgs pr) {
    int z = blockIdx.z;
    const unsigned short* A = pr.A[z];
    const unsigned short* BT = pr.BT[z];
    const float* bias = pr.bias[z];
    unsigned short* C = pr.C[z];
    unsigned short* vtA = pr.vtA[z];
    unsigned short* vtB = pr.vtB[z];
    int svA = pr.svA[z], svB = pr.svB[z];

    // unified LDS: [0,49152) = sA x3 (16384B each), [49152,73728) = sB x3 (8192B each)
    __shared__ __align__(16) char smem[73728];

    // XCD-chunked swizzle: dispatch d (x fastest) -> XCD k=d%8 owns m in
    // {4k..4k+3} over all 24 n-tiles (per-XCD set: A 1MB + B 3MB, L2-fits).
    int d = blockIdx.y * 32 + blockIdx.x;
    int k8 = d & 7, j8 = d >> 3;
    int mt = k8 * 4 + (j8 & 3), nt = j8 >> 2;

    int tid = threadIdx.x, l = tid & 63, w = tid >> 6;
    int m0 = mt * 256, n0 = nt * 128;
    int wm = w >> 1, wn = w & 1;
    int lq = l & 15, lg = l >> 4;

    f32x4 zf = {0.f, 0.f, 0.f, 0.f};
    f32x4 acc[4][4];
#pragma unroll
    for (int i = 0; i < 4; i++)
#pragma unroll
        for (int j = 0; j < 4; j++) acc[i][j] = zf;

    int trow = tid >> 2;
    int tslot = (tid & 3) ^ ((tid >> 2) & 3) ^ ((tid >> 4) & 3);
    const unsigned short* As = A + (m0 + trow) * 512 + tslot * 8;
    const unsigned short* Bs = BT + (n0 + trow) * 512 + tslot * 8;

#define PSTAGE(J, KT)                                                         \
    {                                                                         \
        GLDS16(As + (KT) * 32, smem + (J) * 16384 + tid * 16);                \
        GLDS16(As + (KT) * 32 + 128 * 512,                                    \
               smem + (J) * 16384 + 8192 + tid * 16);                         \
        GLDS16(Bs + (KT) * 32, smem + 49152 + (J) * 8192 + tid * 16);         \
    }

    int rslot8 = (lg ^ (lq & 3) ^ ((lq >> 2) & 3)) * 8;

#define PITER(T, JT, JS, WN)                                                            \
    {                                                                                   \
        asm volatile("s_waitcnt vmcnt(" #WN ")" ::: "memory");                          \
        __builtin_amdgcn_s_barrier();                                                   \
        asm volatile("" ::: "memory");                                                  \
        if ((T) < 14) PSTAGE(JS, (T) + 2);                                              \
        short8 af01[2], bf[4];                                                          \
        _Pragma("unroll") for (int mi = 0; mi < 2; mi++) af01[mi] =                     \
            *(const short8*)(smem + (JT) * 16384 +                                      \
                             ((wm * 64 + mi * 16 + lq) * 32 + rslot8) * 2);             \
        _Pragma("unroll") for (int ni = 0; ni < 4; ni++) bf[ni] =                       \
            *(const short8*)(smem + 49152 + (JT) * 8192 +                               \
                             ((wn * 64 + ni * 16 + lq) * 32 + rslot8) * 2);             \
        __builtin_amdgcn_s_setprio(1);                                                  \
        _Pragma("unroll") for (int mi = 0; mi < 2; mi++)                                \
            _Pragma("unroll") for (int ni = 0; ni < 4; ni++) acc[mi][ni] =              \
                __builtin_amdgcn_mfma_f32_16x16x32_bf16(af01[mi], bf[ni], acc[mi][ni],  \
                                                        0, 0, 0);                       \
        __builtin_amdgcn_s_setprio(0);                                                  \
        __builtin_amdgcn_s_barrier();                                                   \
        short8 af23[2];                                                                 \
        _Pragma("unroll") for (int mi = 0; mi < 2; mi++) af23[mi] =                     \
            *(const short8*)(smem + (JT) * 16384 +                                      \
                             ((wm * 64 + (mi + 2) * 16 + lq) * 32 + rslot8) * 2);       \
        __builtin_amdgcn_s_setprio(1);                                                  \
        _Pragma("unroll") for (int mi = 0; mi < 2; mi++)                                \
            _Pragma("unroll") for (int ni = 0; ni < 4; ni++) acc[mi + 2][ni] =          \
                __builtin_amdgcn_mfma_f32_16x16x32_bf16(af23[mi], bf[ni],               \
                                                        acc[mi + 2][ni], 0, 0, 0);      \
        __builtin_amdgcn_s_setprio(0);                                                  \
    }

    PSTAGE(0, 0)
    PSTAGE(1, 1)
    PITER(0, 0, 2, 3)  PITER(1, 1, 0, 3)  PITER(2, 2, 1, 3)  PITER(3, 0, 2, 3)
    PITER(4, 1, 0, 3)  PITER(5, 2, 1, 3)  PITER(6, 0, 2, 3)  PITER(7, 1, 0, 3)
    PITER(8, 2, 1, 3)  PITER(9, 0, 2, 3)  PITER(10, 1, 0, 3) PITER(11, 2, 1, 3)
    PITER(12, 0, 2, 3) PITER(13, 1, 0, 3) PITER(14, 2, 1, 3) PITER(15, 0, 2, 0)
#undef PITER
#undef PSTAGE

    int s = n0 >> 9;
    bool isV = (s == svA) || (s == svB);
    int col0 = n0 + wn * 64;
    int row0 = m0 + wm * 64;

    __syncthreads();  // all waves done with K-loop LDS; reuse smem per-wave
    char* eb = smem + w * 8192;  // 64 rows x 128B, 16B chunks XOR-swizzled by row&7

    if (!isV) {
#pragma unroll
        for (int mi = 0; mi < 4; mi++)
#pragma unroll
            for (int ni = 0; ni < 4; ni++) {
                int c = ni * 16 + lq;
                float bv = bias[col0 + c];
                int ch = c >> 3;
#pragma unroll
                for (int j = 0; j < 4; j++) {
                    int row = mi * 16 + lg * 4 + j;
                    *(unsigned short*)(eb + row * 128 + ((ch ^ (row & 7)) << 4) +
                                       (c & 7) * 2) = f2bf(acc[mi][ni][j] + bv);
                }
            }
#pragma unroll
        for (int pass = 0; pass < 8; pass++) {
            int row = pass * 8 + (l >> 3);
            int ck = l & 7;
            short8 v = *(const short8*)(eb + row * 128 + ((ck ^ (row & 7)) << 4));
            *(short8*)&C[(size_t)(row0 + row) * 3072 + col0 + ck * 8] = v;
        }
    } else {
        unsigned short* vt = (s == svA) ? vtA : vtB;
        int d0 = col0 - (s << 9);
        int bb = row0 >> 10, nb0 = row0 & 1023;
#pragma unroll
        for (int mi = 0; mi < 4; mi++)
#pragma unroll
            for (int ni = 0; ni < 4; ni++) {
                int dd = ni * 16 + lq;         // local row of [d][n] tile
                float bv = bias[col0 + dd];
                int n = mi * 16 + lg * 4;      // local col base (4 consecutive)
                ushort4v o;
#pragma unroll
                for (int j = 0; j < 4; j++) o[j] = f2bf(acc[mi][ni][j] + bv);
                *(ushort4v*)(eb + dd * 128 + (((n >> 3) ^ (dd & 7)) << 4) + (n & 7) * 2) = o;
            }
#pragma unroll
        for (int pass = 0; pass < 8; pass++) {
            int row = pass * 8 + (l >> 3);      // local d
            int ck = l & 7;
            short8 v = *(const short8*)(eb + row * 128 + ((ck ^ (row & 7)) << 4));
            *(short8*)&vt[(size_t)(bb * 512 + d0 + row) * 1024 + nb0 + ck * 8] = v;
        }
    }
}

// ---------------- flash attention (8-wave blocks: shared K/V staging) ----------------
// grid.x = 4 branches * 8 b * 8 h * 4 qtiles = 1024 blocks of 512 threads.
// Each staged K/V tile feeds 8 waves (vs 4): LDS-DMA traffic halved; waves 0-3
// stage K, waves 4-7 stage V (1 glds/thread/tile). Compute per wave identical
// to the proven round-7 body (bit-identical numerics). Chunked XCD swizzle for
// 4 sharers/set; no-max softmax, ones-MFMA row-sum, setprio.
__global__ __launch_bounds__(512) void k_attn(const unsigned short* __restrict__ PX,
                                              const unsigned short* __restrict__ PY,
                                              const unsigned short* __restrict__ VT0,
                                              const unsigned short* __restrict__ VT1,
                                              const unsigned short* __restrict__ VT2,
                                              const unsigned short* __restrict__ VT3,
                                              unsigned short* __restrict__ Ox,
                                              unsigned short* __restrict__ Oy) {
    int bid = blockIdx.x;
    // bijective: bid = g*32 + s*8 + x  ->  id = g*32 + x*4 + s ; the 4 qtiles
    // sharing one (br,b,h) K/V set are bids {g*32 + s*8 + x} -> same XCD x.
    int id = ((bid >> 5) << 5) | ((bid & 7) << 2) | ((bid >> 3) & 3);
    int br = id >> 8, b = (id >> 5) & 7, h = (id >> 2) & 7, qt = id & 3;

    const int qcol_t[4] = {0, 1536, 1024, 1536};
    const int kcol_t[4] = {512, 0, 2048, 2048};
    const int ocol_t[4] = {0, 512, 0, 512};
    const unsigned short* Pq = (br < 2) ? PX : PY;
    const unsigned short* Pk = (br == 0 || br == 2) ? PX : PY;
    const unsigned short* VT = (br == 0) ? VT0 : (br == 1) ? VT1 : (br == 2) ? VT2 : VT3;
    unsigned short* O = (br < 2) ? Ox : Oy;

    const unsigned short* Qp = Pq + (b * 1024) * 3072 + qcol_t[br] + h * 64;
    const unsigned short* Kp = Pk + (b * 1024) * 3072 + kcol_t[br] + h * 64;
    const unsigned short* Vp = VT + (b * 512 + h * 64) * 1024;
    unsigned short* Op = O + (b * 1024) * 1024 + ocol_t[br] + h * 64;

    int tid = threadIdx.x, l = tid & 63, w = tid >> 6;
    int q0 = qt * 256 + w * 32;
    int lq = l & 15, lg = l >> 4;

    __shared__ __align__(16) unsigned short sK[2][32 * 64];    // [kv][d], slot^=(row&7)
    __shared__ __align__(16) unsigned short sV[2][64 * 32];    // [d][kv], slot^=((row>>1)&3)
    __shared__ __align__(16) unsigned short pBuf[8][32 * 32];  // per-wave P, sV swizzle

    short8 qf[2][2];
#pragma unroll
    for (int cb = 0; cb < 2; cb++)
#pragma unroll
        for (int kc = 0; kc < 2; kc++)
            qf[cb][kc] = *(const short8*)&Qp[(q0 + cb * 16 + lq) * 3072 + kc * 32 + lg * 8];

    f32x4 zf = {0.f, 0.f, 0.f, 0.f};
    f32x4 acc[2][4];
#pragma unroll
    for (int i = 0; i < 2; i++)
#pragma unroll
        for (int j = 0; j < 4; j++) acc[i][j] = zf;
    f32x4 sum_acc[2] = {zf, zf};  // ones-MFMA row-sum accumulator
    const unsigned short one_bf = 0x3F80;
    short8 onesf = {(short)one_bf, (short)one_bf, (short)one_bf, (short)one_bf,
                    (short)one_bf, (short)one_bf, (short)one_bf, (short)one_bf};

    // staging split: tid<256 stage K, tid>=256 stage V (1 glds/thread/tile).
    // Pre-swizzled global sources (rule 21: linear LDS dst + inverse-swz src).
    int t2 = tid & 255;
    bool isK = tid < 256;
    const unsigned short* gsrc =
        isK ? (Kp + (t2 >> 3) * 3072 + (((t2 & 7) ^ ((t2 >> 3) & 7)) * 8))
            : (Vp + (t2 >> 2) * 1024 + (((t2 & 3) ^ ((t2 >> 3) & 3)) * 8));
    long gstep = isK ? (long)(32 * 3072) : 32;  // per-tile advance (elements)
    char* lds0 = (isK ? (char*)&sK[0][0] : (char*)&sV[0][0]) + t2 * 16;
    char* lds1 = (isK ? (char*)&sK[1][0] : (char*)&sV[1][0]) + t2 * 16;
    int swq = (lq >> 1) & 3;  // row-phase swizzle bits for sV/pBuf reads

#define ATTN_COMPUTE(CUR)                                                                       \
    {                                                                                           \
        short8 kf[2][2];                                                                        \
        _Pragma("unroll") for (int rb = 0; rb < 2; rb++) _Pragma("unroll") for (int kc = 0;     \
                                                                                kc < 2; kc++)   \
            kf[rb][kc] = *(const short8*)&sK[CUR][(rb * 16 + lq) * 64 +                         \
                                                  (((kc * 4 + lg) ^ (lq & 7)) * 8)];            \
        f32x4 st[2][2];                                                                         \
        __builtin_amdgcn_s_setprio(1);                                                          \
        _Pragma("unroll") for (int rb = 0; rb < 2; rb++) _Pragma("unroll") for (int cb = 0;     \
                                                                                cb < 2; cb++) { \
            f32x4 s0 = __builtin_amdgcn_mfma_f32_16x16x32_bf16(kf[rb][0], qf[cb][0], zf, 0, 0,  \
                                                               0);                              \
            st[rb][cb] = __builtin_amdgcn_mfma_f32_16x16x32_bf16(kf[rb][1], qf[cb][1], s0, 0,   \
                                                                 0, 0);                         \
        }                                                                                       \
        __builtin_amdgcn_s_setprio(0);                                                          \
        unsigned int pw[2][2][2];                                                               \
        _Pragma("unroll") for (int cb = 0; cb < 2; cb++) _Pragma("unroll") for (int rb = 0;     \
                                                                                rb < 2; rb++) { \
            float p0 = __builtin_amdgcn_exp2f(st[rb][cb][0]);                                   \
            float p1 = __builtin_amdgcn_exp2f(st[rb][cb][1]);                                   \
            float p2 = __builtin_amdgcn_exp2f(st[rb][cb][2]);                                   \
            float p3 = __builtin_amdgcn_exp2f(st[rb][cb][3]);                                   \
            pw[cb][rb][0] = pkP(p0, p1);                                                        \
            pw[cb][rb][1] = pkP(p2, p3);                                                        \
        }                                                                                       \
        _Pragma("unroll") for (int cb = 0; cb < 2; cb++) _Pragma("unroll") for (int rb = 0;     \
                                                                                rb < 2; rb++) { \
            int row = cb * 16 + lq;                                                             \
            int sl = (rb * 2 + (lg >> 1)) ^ swq;                                                \
            unsigned long long pk8 = ((unsigned long long)pw[cb][rb][1] << 32) | pw[cb][rb][0]; \
            *(unsigned long long*)&pBuf[w][row * 32 + sl * 8 + (lg & 1) * 4] = pk8;             \
        }                                                                                       \
        short8 pa[2];                                                                           \
        pa[0] = *(const short8*)&pBuf[w][lq * 32 + ((lg ^ swq) * 8)];                           \
        pa[1] = *(const short8*)&pBuf[w][(16 + lq) * 32 + ((lg ^ swq) * 8)];                    \
        short8 vf[4];                                                                           \
        _Pragma("unroll") for (int nb = 0; nb < 4; nb++) vf[nb] =                               \
            *(const short8*)&sV[CUR][(nb * 16 + lq) * 32 + ((lg ^ swq) * 8)];                   \
        __builtin_amdgcn_s_setprio(1);                                                          \
        _Pragma("unroll") for (int qb = 0; qb < 2; qb++) {                                      \
            sum_acc[qb] =                                                                       \
                __builtin_amdgcn_mfma_f32_16x16x32_bf16(pa[qb], onesf, sum_acc[qb], 0, 0, 0);   \
            _Pragma("unroll") for (int nb = 0; nb < 4; nb++) acc[qb][nb] =                      \
                __builtin_amdgcn_mfma_f32_16x16x32_bf16(pa[qb], vf[nb], acc[qb][nb], 0, 0, 0);  \
        }                                                                                       \
        __builtin_amdgcn_s_setprio(0);                                                          \
        __syncthreads();                                                                        \
    }

    // prologue: stage tile 0 into buf0 (1 glds per thread)
    GLDS16(gsrc, lds0);
    gsrc += gstep;
    __syncthreads();

    for (int t = 0; t < 32; t += 2) {
        // tile t from buf0; prefetch tile t+1 into buf1 (t+1 <= 31 always)
        GLDS16(gsrc, lds1);
        gsrc += gstep;
        ATTN_COMPUTE(0)
        // tile t+1 from buf1; prefetch tile t+2 into buf0 unless done
        if (t < 30) {
            GLDS16(gsrc, lds0);
            gsrc += gstep;
        }
        ATTN_COMPUTE(1)
    }
#undef ATTN_COMPUTE

    // sum_acc[qb][j] = row-sum for O row lg*4+j -> no shuffles
#pragma unroll
    for (int qb = 0; qb < 2; qb++) {
        f32x4 rv;
#pragma unroll
        for (int j = 0; j < 4; j++) rv[j] = 1.f / sum_acc[qb][j];
#pragma unroll
        for (int nb = 0; nb < 4; nb++) {
            int d = nb * 16 + lq;
            int r = q0 + qb * 16 + lg * 4;
#pragma unroll
            for (int j = 0; j < 4; j++) {
                float o = acc[qb][nb][j] * rv[j] + bf2f(Qp[(r + j) * 3072 + d]);
                Op[(r + j) * 1024 + d] = f2bf(o);
            }
        }
    }
}

// ---------------- output GEMM (counted-vmcnt) + bias + relu + residual ----------------
// out[8192][512] (x2) = Ocat[8192][1024] @ W^T[512][1024]^T; BM=256, BN=128,
// BK=32, 32 K-iters, 512 threads, 3-buffer rotation, vmcnt(3) + raw barrier.
__global__ __launch_bounds__(512) void k_final(const unsigned short* __restrict__ Ax,
                                               const unsigned short* __restrict__ Ay,
                                               const unsigned short* __restrict__ BTx,
                                               const unsigned short* __restrict__ BTy,
                                               const float* __restrict__ bx,
                                               const float* __restrict__ by,
                                               const float* __restrict__ X,
                                               const float* __restrict__ Y,
                                               float* __restrict__ out) {
    int z = blockIdx.z;
    const unsigned short* A = z ? Ay : Ax;
    const unsigned short* BT = z ? BTy : BTx;
    const float* bias = z ? by : bx;
    const float* R = z ? Y : X;
    float* o = out + z * 4194304;

    __shared__ __align__(16) unsigned short sA[3][256 * 32];
    __shared__ __align__(16) unsigned short sB[3][128 * 32];
    int tid = threadIdx.x, l = tid & 63, w = tid >> 6;
    int m0 = blockIdx.x * 256, n0 = blockIdx.y * 128;
    int wm = w >> 1, wn = w & 1;
    int lq = l & 15, lg = l >> 4;

    f32x4 zf = {0.f, 0.f, 0.f, 0.f};
    f32x4 acc[4][4];
#pragma unroll
    for (int i = 0; i < 4; i++)
#pragma unroll
        for (int j = 0; j < 4; j++) acc[i][j] = zf;

    int trow = tid >> 2;
    int tslot = (tid & 3) ^ ((tid >> 2) & 3) ^ ((tid >> 4) & 3);
    const unsigned short* As = A + (m0 + trow) * 1024 + tslot * 8;
    const unsigned short* Bs = BT + (n0 + trow) * 1024 + tslot * 8;

#define FSTAGE(J, KT)                                                        \
    {                                                                        \
        GLDS16(As + (KT) * 32, (char*)sA + (J) * 16384 + tid * 16);          \
        GLDS16(As + (KT) * 32 + 128 * 1024,                                  \
               (char*)sA + (J) * 16384 + 8192 + tid * 16);                   \
        GLDS16(Bs + (KT) * 32, (char*)sB + (J) * 8192 + tid * 16);           \
    }

    int rslot8 = (lg ^ (lq & 3) ^ ((lq >> 2) & 3)) * 8;

#define FITER(T, JT, JS, WN)                                                            \
    {                                                                                   \
        asm volatile("s_waitcnt vmcnt(" #WN ")" ::: "memory");                          \
        __builtin_amdgcn_s_barrier();                                                   \
        asm volatile("" ::: "memory");                                                  \
        if ((T) < 30) FSTAGE(JS, (T) + 2);                                              \
        short8 af[4], bf[4];                                                            \
        _Pragma("unroll") for (int mi = 0; mi < 4; mi++) af[mi] =                       \
            *(const short8*)&sA[JT][(wm * 64 + mi * 16 + lq) * 32 + rslot8];            \
        _Pragma("unroll") for (int ni = 0; ni < 4; ni++) bf[ni] =                       \
            *(const short8*)&sB[JT][(wn * 64 + ni * 16 + lq) * 32 + rslot8];            \
        __builtin_amdgcn_s_setprio(1);                                                  \
        _Pragma("unroll") for (int mi = 0; mi < 4; mi++)                                \
            _Pragma("unroll") for (int ni = 0; ni < 4; ni++) acc[mi][ni] =              \
                __builtin_amdgcn_mfma_f32_16x16x32_bf16(af[mi], bf[ni], acc[mi][ni],    \
                                                        0, 0, 0);                       \
        __builtin_amdgcn_s_setprio(0);                                                  \
    }

    FSTAGE(0, 0)
    FSTAGE(1, 1)
    FITER(0, 0, 2, 3)  FITER(1, 1, 0, 3)  FITER(2, 2, 1, 3)  FITER(3, 0, 2, 3)
    FITER(4, 1, 0, 3)  FITER(5, 2, 1, 3)  FITER(6, 0, 2, 3)  FITER(7, 1, 0, 3)
    FITER(8, 2, 1, 3)  FITER(9, 0, 2, 3)  FITER(10, 1, 0, 3) FITER(11, 2, 1, 3)
    FITER(12, 0, 2, 3) FITER(13, 1, 0, 3) FITER(14, 2, 1, 3) FITER(15, 0, 2, 3)
    FITER(16, 1, 0, 3) FITER(17, 2, 1, 3) FITER(18, 0, 2, 3) FITER(19, 1, 0, 3)
    FITER(20, 2, 1, 3) FITER(21, 0, 2, 3) FITER(22, 1, 0, 3) FITER(23, 2, 1, 3)
    FITER(24, 0, 2, 3) FITER(25, 1, 0, 3) FITER(26, 2, 1, 3) FITER(27, 0, 2, 3)
    FITER(28, 1, 0, 3) FITER(29, 2, 1, 3) FITER(30, 0, 2, 3) FITER(31, 1, 0, 0)
#undef FITER
#undef FSTAGE

    int col0 = n0 + wn * 64;
    int row0 = m0 + wm * 64;
#pragma unroll
    for (int mi = 0; mi < 4; mi++)
#pragma unroll
        for (int ni = 0; ni < 4; ni++) {
            int c = col0 + ni * 16 + lq;
            float bv = bias[c];
            int r = row0 + mi * 16 + lg * 4;
#pragma unroll
            for (int j = 0; j < 4; j++) {
                int idx = (r + j) * 512 + c;
                o[idx] = R[idx] + fmaxf(0.f, acc[mi][ni][j] + bv);
            }
        }
}

// ---------------- host ----------------
extern "C" void kernel_launch(void* const* d_in, const int* in_sizes, int n_in, void* d_out,
                              int out_size, void* d_ws, size_t ws_size, hipStream_t stream) {
    (void)in_sizes; (void)n_in; (void)out_size; (void)ws_size;
    char* ws = (char*)d_ws;
    unsigned short* Xb = (unsigned short*)(ws + OFF_XB);
    unsigned short* Yb = (unsigned short*)(ws + OFF_YB);
    unsigned short* WcatXT = (unsigned short*)(ws + OFF_WCXT);
    unsigned short* WcatYT = (unsigned short*)(ws + OFF_WCYT);
    unsigned short* WXT = (unsigned short*)(ws + OFF_WXT);
    unsigned short* WYT = (unsigned short*)(ws + OFF_WYT);
    float* biasX = (float*)(ws + OFF_BX);
    float* biasY = (float*)(ws + OFF_BY);
    unsigned short* PX = (unsigned short*)(ws + OFF_PX);
    unsigned short* PY = (unsigned short*)(ws + OFF_PY);
    unsigned short* VTxx = (unsigned short*)(ws + OFF_VT0);
    unsigned short* VTxy = (unsigned short*)(ws + OFF_VT1);
    unsigned short* VTyx = (unsigned short*)(ws + OFF_VT2);
    unsigned short* VTyy = (unsigned short*)(ws + OFF_VT3);
    unsigned short* Oxc = (unsigned short*)(ws + OFF_OX);
    unsigned short* Oyc = (unsigned short*)(ws + OFF_OY);

    // X-side cat order s=0..5: q_xx,k_xx,v_xx,q_xy,k_yx,v_yx
    // Y-side cat order s=0..5: k_xy,v_xy,q_yx,q_yy,k_yy,v_yy
    const int wiX[6] = {2, 4, 6, 8, 16, 18};
    const int wiY[6] = {10, 12, 14, 20, 22, 24};
    PackA pa;
    for (int i = 0; i < 6; i++) {
        pa.w[i] = (const float*)d_in[wiX[i]];
        pa.b[i] = (const float*)d_in[wiX[i] + 1];
        pa.w[6 + i] = (const float*)d_in[wiY[i]];
        pa.b[6 + i] = (const float*)d_in[wiY[i] + 1];
    }
    pa.wox = (const float*)d_in[26];
    pa.woy = (const float*)d_in[28];
    pa.X = (const float*)d_in[0];
    pa.Y = (const float*)d_in[1];

    k_pack<<<dim3(16, 32, 30), dim3(32, 8), 0, stream>>>(pa, WcatXT, WcatYT, biasX, biasY, WXT,
                                                         WYT, Xb, Yb);

    ProjArgs pr;
    pr.A[0] = Xb;        pr.A[1] = Yb;
    pr.BT[0] = WcatXT;   pr.BT[1] = WcatYT;
    pr.bias[0] = biasX;  pr.bias[1] = biasY;
    pr.C[0] = PX;        pr.C[1] = PY;
    pr.vtA[0] = VTxx;    pr.vtA[1] = VTxy;
    pr.svA[0] = 2;       pr.svA[1] = 1;
    pr.vtB[0] = VTyx;    pr.vtB[1] = VTyy;
    pr.svB[0] = 5;       pr.svB[1] = 5;
    k_proj<<<dim3(32, 24, 2), 512, 0, stream>>>(pr);

    k_attn<<<1024, 512, 0, stream>>>(PX, PY, VTxx, VTxy, VTyx, VTyy, Oxc, Oyc);

    k_final<<<dim3(32, 4, 2), 512, 0, stream>>>(Oxc, Oyc, WXT, WYT, (const float*)d_in[27],
                                                (const float*)d_in[29], (const float*)d_in[0],
                                                (const float*)d_in[1], (float*)d_out);
}

// Round 18
// 187.608 us; speedup vs baseline: 1.0234x; 1.0234x over previous
//
#include <hip/hip_runtime.h>
#include <stdint.h>
#include <math.h>

typedef __attribute__((ext_vector_type(8))) short short8;
typedef __attribute__((ext_vector_type(4))) float f32x4;
typedef __attribute__((ext_vector_type(4))) unsigned short ushort4v;

#define DEV static __device__ __forceinline__

DEV unsigned short f2bf(float f) {
    unsigned int u = __float_as_uint(f);
    u += 0x7fffu + ((u >> 16) & 1u);
    return (unsigned short)(u >> 16);
}
DEV float bf2f(unsigned short h) { return __uint_as_float(((unsigned int)h) << 16); }
// pack trunc-bf16(a) low, trunc-bf16(b) high — single v_perm_b32
DEV unsigned int pkP(float a, float b) {
    return __builtin_amdgcn_perm(__float_as_uint(b), __float_as_uint(a), 0x07060302u);
}

#define GLDS16(g, l)                                                                     \
    __builtin_amdgcn_global_load_lds((const __attribute__((address_space(1))) void*)(g), \
                                     (__attribute__((address_space(3))) void*)(l), 16, 0, 0)

// ---------------- workspace layout (bytes) ----------------
static const size_t OFF_XB   = 0;                       // X bf16 [8192][512]
static const size_t OFF_YB   = 8388608;                 // Y bf16
static const size_t OFF_WCXT = 16777216;                // WcatX^T bf16 [3072][512]
static const size_t OFF_WCYT = 19922944;                // WcatY^T
static const size_t OFF_WXT  = 23068672;                // W_X^T bf16 [512][1024]
static const size_t OFF_WYT  = 24117248;                // W_Y^T
static const size_t OFF_BX   = 25165824;                // biasX f32 [3072]
static const size_t OFF_BY   = 25178112;                // biasY f32 [3072]
static const size_t OFF_PX   = 25190400;                // PX bf16 [8192][3072]
static const size_t OFF_PY   = 75522048;                // PY bf16
static const size_t OFF_VT0  = 125853696;               // VT_xx bf16 [8][512][1024]
static const size_t OFF_VT1  = 134242304;               // VT_xy
static const size_t OFF_VT2  = 142630912;               // VT_yx
static const size_t OFF_VT3  = 151019520;               // VT_yy
static const size_t OFF_OX   = 159408128;               // Ocat_x bf16 [8192][1024]
static const size_t OFF_OY   = 176185344;               // Ocat_y

// ---------------- pack + cast (merged) ----------------
struct PackA {
    const float* w[12];
    const float* b[12];
    const float* wox;   // W_X [1024][512]
    const float* woy;   // W_Y
    const float* X;
    const float* Y;
};

// z in [0,12): Wcat pack (K-branches z in {1,4,6,10} pre-scaled by
// cs = log2(e)/sqrt(512) so QK^T emerges in log2 units -> softmax = raw exp2).
// z in {12,13}: W_X / W_Y transpose-pack.  z in [14,30): X/Y f32->bf16 cast.
__global__ __launch_bounds__(256) void k_pack(PackA p, unsigned short* WcatXT,
                                              unsigned short* WcatYT, float* biasX, float* biasY,
                                              unsigned short* WXT, unsigned short* WYT,
                                              unsigned short* Xb, unsigned short* Yb) {
    int z = blockIdx.z;
    __shared__ float tile[32][33];
    int tx = threadIdx.x, ty = threadIdx.y;
    if (z >= 14) {
        int flat = (blockIdx.y * 16 + blockIdx.x) * 256 + ty * 32 + tx;
        int q = (z - 14) * 131072 + flat;  // float4 index over X then Y
        const int NE = 1048576;
        const float* s;
        unsigned short* d;
        if (q < NE) { s = p.X; d = Xb; } else { s = p.Y; d = Yb; q -= NE; }
        float4 v = ((const float4*)s)[q];
        ushort4v o = {f2bf(v.x), f2bf(v.y), f2bf(v.z), f2bf(v.w)};
        ((ushort4v*)d)[q] = o;
        return;
    }
    if (z < 12) {
        if (blockIdx.y >= 16) return;
        const float sc = (z == 1 || z == 4 || z == 6 || z == 10) ? 0.0637587160f : 1.0f;
        const float* src = p.w[z];
        unsigned short* dst = (z < 6) ? (WcatXT + z * 262144) : (WcatYT + (z - 6) * 262144);
        int x = blockIdx.x * 32 + tx;
        int y0 = blockIdx.y * 32 + ty;
#pragma unroll
        for (int j = 0; j < 4; j++) tile[ty + j * 8][tx] = src[(y0 + j * 8) * 512 + x];
        __syncthreads();
        int x2 = blockIdx.y * 32 + tx;
        int y2 = blockIdx.x * 32 + ty;
#pragma unroll
        for (int j = 0; j < 4; j++)
            dst[(y2 + j * 8) * 512 + x2] = f2bf(sc * tile[tx][ty + j * 8]);
        if (blockIdx.x == 0 && blockIdx.y == 0) {
            int t = ty * 32 + tx;
            float* bd = (z < 6) ? (biasX + z * 512) : (biasY + (z - 6) * 512);
            bd[t] = sc * p.b[z][t];
            bd[t + 256] = sc * p.b[z][t + 256];
        }
    } else {
        const float* src = (z == 13) ? p.woy : p.wox;       // [1024][512]
        unsigned short* dst = (z == 13) ? WYT : WXT;        // [512][1024]
        int x = blockIdx.x * 32 + tx;                       // src col 0..511
        int y0 = blockIdx.y * 32 + ty;                      // src row 0..1023
#pragma unroll
        for (int j = 0; j < 4; j++) tile[ty + j * 8][tx] = src[(y0 + j * 8) * 512 + x];
        __syncthreads();
        int x2 = blockIdx.y * 32 + tx;
        int y2 = blockIdx.x * 32 + ty;
#pragma unroll
        for (int j = 0; j < 4; j++) dst[(y2 + j * 8) * 1024 + x2] = f2bf(tile[tx][ty + j * 8]);
    }
}

// ---------------- projection GEMM (counted-vmcnt + LDS-staged epilogue) ----------------
// C[8192][3072] = A[8192][512] @ BT[3072][512]^T + bias, bf16 out.
// BM=256, BN=128, BK=32; 512 threads = 8 waves; 3 LDS buffers rotate; tile T+2
// staged while computing T; s_waitcnt vmcnt(3) + raw s_barrier per K-tile.
// Epilogue: per-wave 64x64 tile staged in LDS (XOR-swizzled 16B chunks), then
// 8 global_store_dwordx4/thread (8x128B contiguous segments per instruction).
// V regions (s==svA || s==svB) stored transposed into vt: [b][d][n], same path.
struct ProjArgs {
    const unsigned short* A[2];
    const unsigned short* BT[2];
    const float* bias[2];
    unsigned short* C[2];
    unsigned short* vtA[2];
    unsigned short* vtB[2];
    int svA[2], svB[2];
};

__global__ __launch_bounds__(512) void k_proj(ProjArgs pr) {
    int z = blockIdx.z;
    const unsigned short* A = pr.A[z];
    const unsigned short* BT = pr.BT[z];
    const float* bias = pr.bias[z];
    unsigned short* C = pr.C[z];
    unsigned short* vtA = pr.vtA[z];
    unsigned short* vtB = pr.vtB[z];
    int svA = pr.svA[z], svB = pr.svB[z];

    // unified LDS: [0,49152) = sA x3 (16384B each), [49152,73728) = sB x3 (8192B each)
    __shared__ __align__(16) char smem[73728];

    int tid = threadIdx.x, l = tid & 63, w = tid >> 6;
    int m0 = blockIdx.x * 256, n0 = blockIdx.y * 128;
    int wm = w >> 1, wn = w & 1;
    int lq = l & 15, lg = l >> 4;

    f32x4 zf = {0.f, 0.f, 0.f, 0.f};
    f32x4 acc[4][4];
#pragma unroll
    for (int i = 0; i < 4; i++)
#pragma unroll
        for (int j = 0; j < 4; j++) acc[i][j] = zf;

    int trow = tid >> 2;
    int tslot = (tid & 3) ^ ((tid >> 2) & 3) ^ ((tid >> 4) & 3);
    const unsigned short* As = A + (m0 + trow) * 512 + tslot * 8;
    const unsigned short* Bs = BT + (n0 + trow) * 512 + tslot * 8;

#define PSTAGE(J, KT)                                                         \
    {                                                                         \
        GLDS16(As + (KT) * 32, smem + (J) * 16384 + tid * 16);                \
        GLDS16(As + (KT) * 32 + 128 * 512,                                    \
               smem + (J) * 16384 + 8192 + tid * 16);                         \
        GLDS16(Bs + (KT) * 32, smem + 49152 + (J) * 8192 + tid * 16);         \
    }

    int rslot8 = (lg ^ (lq & 3) ^ ((lq >> 2) & 3)) * 8;

#define PITER(T, JT, JS, WN)                                                            \
    {                                                                                   \
        asm volatile("s_waitcnt vmcnt(" #WN ")" ::: "memory");                          \
        __builtin_amdgcn_s_barrier();                                                   \
        asm volatile("" ::: "memory");                                                  \
        if ((T) < 14) PSTAGE(JS, (T) + 2);                                              \
        short8 af[4], bf[4];                                                            \
        _Pragma("unroll") for (int mi = 0; mi < 4; mi++) af[mi] =                       \
            *(const short8*)(smem + (JT) * 16384 +                                      \
                             ((wm * 64 + mi * 16 + lq) * 32 + rslot8) * 2);             \
        _Pragma("unroll") for (int ni = 0; ni < 4; ni++) bf[ni] =                       \
            *(const short8*)(smem + 49152 + (JT) * 8192 +                               \
                             ((wn * 64 + ni * 16 + lq) * 32 + rslot8) * 2);             \
        __builtin_amdgcn_s_setprio(1);                                                  \
        _Pragma("unroll") for (int mi = 0; mi < 4; mi++)                                \
            _Pragma("unroll") for (int ni = 0; ni < 4; ni++) acc[mi][ni] =              \
                __builtin_amdgcn_mfma_f32_16x16x32_bf16(af[mi], bf[ni], acc[mi][ni],    \
                                                        0, 0, 0);                       \
        __builtin_amdgcn_s_setprio(0);                                                  \
    }

    PSTAGE(0, 0)
    PSTAGE(1, 1)
    PITER(0, 0, 2, 3)  PITER(1, 1, 0, 3)  PITER(2, 2, 1, 3)  PITER(3, 0, 2, 3)
    PITER(4, 1, 0, 3)  PITER(5, 2, 1, 3)  PITER(6, 0, 2, 3)  PITER(7, 1, 0, 3)
    PITER(8, 2, 1, 3)  PITER(9, 0, 2, 3)  PITER(10, 1, 0, 3) PITER(11, 2, 1, 3)
    PITER(12, 0, 2, 3) PITER(13, 1, 0, 3) PITER(14, 2, 1, 3) PITER(15, 0, 2, 0)
#undef PITER
#undef PSTAGE

    int s = n0 >> 9;
    bool isV = (s == svA) || (s == svB);
    int col0 = n0 + wn * 64;
    int row0 = m0 + wm * 64;

    __syncthreads();  // all waves done with K-loop LDS; reuse smem per-wave
    char* eb = smem + w * 8192;  // 64 rows x 128B, 16B chunks XOR-swizzled by row&7

    if (!isV) {
        // frag write: lane's 4 j-values = 4 rows of column c (2B each, ~2 lanes/bank)
#pragma unroll
        for (int mi = 0; mi < 4; mi++)
#pragma unroll
            for (int ni = 0; ni < 4; ni++) {
                int c = ni * 16 + lq;
                float bv = bias[col0 + c];
                int ch = c >> 3;
#pragma unroll
                for (int j = 0; j < 4; j++) {
                    int row = mi * 16 + lg * 4 + j;
                    *(unsigned short*)(eb + row * 128 + ((ch ^ (row & 7)) << 4) +
                                       (c & 7) * 2) = f2bf(acc[mi][ni][j] + bv);
                }
            }
        // wave-private readback (same-wave RAW ordered by lgkmcnt) + wide stores
#pragma unroll
        for (int pass = 0; pass < 8; pass++) {
            int row = pass * 8 + (l >> 3);
            int ck = l & 7;
            short8 v = *(const short8*)(eb + row * 128 + ((ck ^ (row & 7)) << 4));
            *(short8*)&C[(size_t)(row0 + row) * 3072 + col0 + ck * 8] = v;
        }
    } else {
        unsigned short* vt = (s == svA) ? vtA : vtB;
        int d0 = col0 - (s << 9);
        int bb = row0 >> 10, nb0 = row0 & 1023;
        // frag write: lane's 4 j-values = 4 consecutive n of one d -> one 8B write
#pragma unroll
        for (int mi = 0; mi < 4; mi++)
#pragma unroll
            for (int ni = 0; ni < 4; ni++) {
                int d = ni * 16 + lq;          // local row of [d][n] tile
                float bv = bias[col0 + d];
                int n = mi * 16 + lg * 4;      // local col base (4 consecutive)
                ushort4v o;
#pragma unroll
                for (int j = 0; j < 4; j++) o[j] = f2bf(acc[mi][ni][j] + bv);
                *(ushort4v*)(eb + d * 128 + (((n >> 3) ^ (d & 7)) << 4) + (n & 7) * 2) = o;
            }
#pragma unroll
        for (int pass = 0; pass < 8; pass++) {
            int row = pass * 8 + (l >> 3);      // local d
            int ck = l & 7;
            short8 v = *(const short8*)(eb + row * 128 + ((ck ^ (row & 7)) << 4));
            *(short8*)&vt[(size_t)(bb * 512 + d0 + row) * 1024 + nb0 + ck * 8] = v;
        }
    }
}

// ---------------- flash attention (8-wave blocks: shared K/V staging) ----------------
// grid.x = 4 branches * 8 b * 8 h * 4 qtiles = 1024 blocks of 512 threads.
// Each staged K/V tile feeds 8 waves (vs 4): LDS-DMA traffic halved; waves 0-3
// stage K, waves 4-7 stage V (1 glds/thread/tile). Compute per wave identical
// to the proven round-7 body (bit-identical numerics). Chunked XCD swizzle for
// 4 sharers/set; no-max softmax, ones-MFMA row-sum, setprio.
__global__ __launch_bounds__(512) void k_attn(const unsigned short* __restrict__ PX,
                                              const unsigned short* __restrict__ PY,
                                              const unsigned short* __restrict__ VT0,
                                              const unsigned short* __restrict__ VT1,
                                              const unsigned short* __restrict__ VT2,
                                              const unsigned short* __restrict__ VT3,
                                              unsigned short* __restrict__ Ox,
                                              unsigned short* __restrict__ Oy) {
    int bid = blockIdx.x;
    // bijective: bid = g*32 + s*8 + x  ->  id = g*32 + x*4 + s ; the 4 qtiles
    // sharing one (br,b,h) K/V set are bids {g*32 + s*8 + x} -> same XCD x.
    int id = ((bid >> 5) << 5) | ((bid & 7) << 2) | ((bid >> 3) & 3);
    int br = id >> 8, b = (id >> 5) & 7, h = (id >> 2) & 7, qt = id & 3;

    const int qcol_t[4] = {0, 1536, 1024, 1536};
    const int kcol_t[4] = {512, 0, 2048, 2048};
    const int ocol_t[4] = {0, 512, 0, 512};
    const unsigned short* Pq = (br < 2) ? PX : PY;
    const unsigned short* Pk = (br == 0 || br == 2) ? PX : PY;
    const unsigned short* VT = (br == 0) ? VT0 : (br == 1) ? VT1 : (br == 2) ? VT2 : VT3;
    unsigned short* O = (br < 2) ? Ox : Oy;

    const unsigned short* Qp = Pq + (b * 1024) * 3072 + qcol_t[br] + h * 64;
    const unsigned short* Kp = Pk + (b * 1024) * 3072 + kcol_t[br] + h * 64;
    const unsigned short* Vp = VT + (b * 512 + h * 64) * 1024;
    unsigned short* Op = O + (b * 1024) * 1024 + ocol_t[br] + h * 64;

    int tid = threadIdx.x, l = tid & 63, w = tid >> 6;
    int q0 = qt * 256 + w * 32;
    int lq = l & 15, lg = l >> 4;

    __shared__ __align__(16) unsigned short sK[2][32 * 64];    // [kv][d], slot^=(row&7)
    __shared__ __align__(16) unsigned short sV[2][64 * 32];    // [d][kv], slot^=((row>>1)&3)
    __shared__ __align__(16) unsigned short pBuf[8][32 * 32];  // per-wave P, sV swizzle

    short8 qf[2][2];
#pragma unroll
    for (int cb = 0; cb < 2; cb++)
#pragma unroll
        for (int kc = 0; kc < 2; kc++)
            qf[cb][kc] = *(const short8*)&Qp[(q0 + cb * 16 + lq) * 3072 + kc * 32 + lg * 8];

    f32x4 zf = {0.f, 0.f, 0.f, 0.f};
    f32x4 acc[2][4];
#pragma unroll
    for (int i = 0; i < 2; i++)
#pragma unroll
        for (int j = 0; j < 4; j++) acc[i][j] = zf;
    f32x4 sum_acc[2] = {zf, zf};  // ones-MFMA row-sum accumulator
    const unsigned short one_bf = 0x3F80;
    short8 onesf = {(short)one_bf, (short)one_bf, (short)one_bf, (short)one_bf,
                    (short)one_bf, (short)one_bf, (short)one_bf, (short)one_bf};

    // staging split: tid<256 stage K, tid>=256 stage V (1 glds/thread/tile).
    // Pre-swizzled global sources (rule 21: linear LDS dst + inverse-swz src).
    int t2 = tid & 255;
    bool isK = tid < 256;
    const unsigned short* gsrc =
        isK ? (Kp + (t2 >> 3) * 3072 + (((t2 & 7) ^ ((t2 >> 3) & 7)) * 8))
            : (Vp + (t2 >> 2) * 1024 + (((t2 & 3) ^ ((t2 >> 3) & 3)) * 8));
    long gstep = isK ? (long)(32 * 3072) : 32;  // per-tile advance (elements)
    char* lds0 = (isK ? (char*)&sK[0][0] : (char*)&sV[0][0]) + t2 * 16;
    char* lds1 = (isK ? (char*)&sK[1][0] : (char*)&sV[1][0]) + t2 * 16;
    int swq = (lq >> 1) & 3;  // row-phase swizzle bits for sV/pBuf reads

#define ATTN_COMPUTE(CUR)                                                                       \
    {                                                                                           \
        short8 kf[2][2];                                                                        \
        _Pragma("unroll") for (int rb = 0; rb < 2; rb++) _Pragma("unroll") for (int kc = 0;     \
                                                                                kc < 2; kc++)   \
            kf[rb][kc] = *(const short8*)&sK[CUR][(rb * 16 + lq) * 64 +                         \
                                                  (((kc * 4 + lg) ^ (lq & 7)) * 8)];            \
        f32x4 st[2][2];                                                                         \
        __builtin_amdgcn_s_setprio(1);                                                          \
        _Pragma("unroll") for (int rb = 0; rb < 2; rb++) _Pragma("unroll") for (int cb = 0;     \
                                                                                cb < 2; cb++) { \
            f32x4 s0 = __builtin_amdgcn_mfma_f32_16x16x32_bf16(kf[rb][0], qf[cb][0], zf, 0, 0,  \
                                                               0);                              \
            st[rb][cb] = __builtin_amdgcn_mfma_f32_16x16x32_bf16(kf[rb][1], qf[cb][1], s0, 0,   \
                                                                 0, 0);                         \
        }                                                                                       \
        __builtin_amdgcn_s_setprio(0);                                                          \
        unsigned int pw[2][2][2];                                                               \
        _Pragma("unroll") for (int cb = 0; cb < 2; cb++) _Pragma("unroll") for (int rb = 0;     \
                                                                                rb < 2; rb++) { \
            float p0 = __builtin_amdgcn_exp2f(st[rb][cb][0]);                                   \
            float p1 = __builtin_amdgcn_exp2f(st[rb][cb][1]);                                   \
            float p2 = __builtin_amdgcn_exp2f(st[rb][cb][2]);                                   \
            float p3 = __builtin_amdgcn_exp2f(st[rb][cb][3]);                                   \
            pw[cb][rb][0] = pkP(p0, p1);                                                        \
            pw[cb][rb][1] = pkP(p2, p3);                                                        \
        }                                                                                       \
        _Pragma("unroll") for (int cb = 0; cb < 2; cb++) _Pragma("unroll") for (int rb = 0;     \
                                                                                rb < 2; rb++) { \
            int row = cb * 16 + lq;                                                             \
            int sl = (rb * 2 + (lg >> 1)) ^ swq;                                                \
            unsigned long long pk8 = ((unsigned long long)pw[cb][rb][1] << 32) | pw[cb][rb][0]; \
            *(unsigned long long*)&pBuf[w][row * 32 + sl * 8 + (lg & 1) * 4] = pk8;             \
        }                                                                                       \
        short8 pa[2];                                                                           \
        pa[0] = *(const short8*)&pBuf[w][lq * 32 + ((lg ^ swq) * 8)];                           \
        pa[1] = *(const short8*)&pBuf[w][(16 + lq) * 32 + ((lg ^ swq) * 8)];                    \
        short8 vf[4];                                                                           \
        _Pragma("unroll") for (int nb = 0; nb < 4; nb++) vf[nb] =                               \
            *(const short8*)&sV[CUR][(nb * 16 + lq) * 32 + ((lg ^ swq) * 8)];                   \
        __builtin_amdgcn_s_setprio(1);                                                          \
        _Pragma("unroll") for (int qb = 0; qb < 2; qb++) {                                      \
            sum_acc[qb] =                                                                       \
                __builtin_amdgcn_mfma_f32_16x16x32_bf16(pa[qb], onesf, sum_acc[qb], 0, 0, 0);   \
            _Pragma("unroll") for (int nb = 0; nb < 4; nb++) acc[qb][nb] =                      \
                __builtin_amdgcn_mfma_f32_16x16x32_bf16(pa[qb], vf[nb], acc[qb][nb], 0, 0, 0);  \
        }                                                                                       \
        __builtin_amdgcn_s_setprio(0);                                                          \
        __syncthreads();                                                                        \
    }

    // prologue: stage tile 0 into buf0 (1 glds per thread)
    GLDS16(gsrc, lds0);
    gsrc += gstep;
    __syncthreads();

    for (int t = 0; t < 32; t += 2) {
        // tile t from buf0; prefetch tile t+1 into buf1 (t+1 <= 31 always)
        GLDS16(gsrc, lds1);
        gsrc += gstep;
        ATTN_COMPUTE(0)
        // tile t+1 from buf1; prefetch tile t+2 into buf0 unless done
        if (t < 30) {
            GLDS16(gsrc, lds0);
            gsrc += gstep;
        }
        ATTN_COMPUTE(1)
    }
#undef ATTN_COMPUTE

    // sum_acc[qb][j] = row-sum for O row lg*4+j -> no shuffles
#pragma unroll
    for (int qb = 0; qb < 2; qb++) {
        f32x4 rv;
#pragma unroll
        for (int j = 0; j < 4; j++) rv[j] = 1.f / sum_acc[qb][j];
#pragma unroll
        for (int nb = 0; nb < 4; nb++) {
            int d = nb * 16 + lq;
            int r = q0 + qb * 16 + lg * 4;
#pragma unroll
            for (int j = 0; j < 4; j++) {
                float o = acc[qb][nb][j] * rv[j] + bf2f(Qp[(r + j) * 3072 + d]);
                Op[(r + j) * 1024 + d] = f2bf(o);
            }
        }
    }
}

// ---------------- output GEMM (counted-vmcnt) + bias + relu + residual ----------------
// out[8192][512] (x2) = Ocat[8192][1024] @ W^T[512][1024]^T; BM=256, BN=128,
// BK=32, 32 K-iters, 512 threads, 3-buffer rotation, vmcnt(3) + raw barrier.
__global__ __launch_bounds__(512) void k_final(const unsigned short* __restrict__ Ax,
                                               const unsigned short* __restrict__ Ay,
                                               const unsigned short* __restrict__ BTx,
                                               const unsigned short* __restrict__ BTy,
                                               const float* __restrict__ bx,
                                               const float* __restrict__ by,
                                               const float* __restrict__ X,
                                               const float* __restrict__ Y,
                                               float* __restrict__ out) {
    int z = blockIdx.z;
    const unsigned short* A = z ? Ay : Ax;
    const unsigned short* BT = z ? BTy : BTx;
    const float* bias = z ? by : bx;
    const float* R = z ? Y : X;
    float* o = out + z * 4194304;

    __shared__ __align__(16) unsigned short sA[3][256 * 32];
    __shared__ __align__(16) unsigned short sB[3][128 * 32];
    int tid = threadIdx.x, l = tid & 63, w = tid >> 6;
    int m0 = blockIdx.x * 256, n0 = blockIdx.y * 128;
    int wm = w >> 1, wn = w & 1;
    int lq = l & 15, lg = l >> 4;

    f32x4 zf = {0.f, 0.f, 0.f, 0.f};
    f32x4 acc[4][4];
#pragma unroll
    for (int i = 0; i < 4; i++)
#pragma unroll
        for (int j = 0; j < 4; j++) acc[i][j] = zf;

    int trow = tid >> 2;
    int tslot = (tid & 3) ^ ((tid >> 2) & 3) ^ ((tid >> 4) & 3);
    const unsigned short* As = A + (m0 + trow) * 1024 + tslot * 8;
    const unsigned short* Bs = BT + (n0 + trow) * 1024 + tslot * 8;

#define FSTAGE(J, KT)                                                        \
    {                                                                        \
        GLDS16(As + (KT) * 32, (char*)sA + (J) * 16384 + tid * 16);          \
        GLDS16(As + (KT) * 32 + 128 * 1024,                                  \
               (char*)sA + (J) * 16384 + 8192 + tid * 16);                   \
        GLDS16(Bs + (KT) * 32, (char*)sB + (J) * 8192 + tid * 16);           \
    }

    int rslot8 = (lg ^ (lq & 3) ^ ((lq >> 2) & 3)) * 8;

#define FITER(T, JT, JS, WN)                                                            \
    {                                                                                   \
        asm volatile("s_waitcnt vmcnt(" #WN ")" ::: "memory");                          \
        __builtin_amdgcn_s_barrier();                                                   \
        asm volatile("" ::: "memory");                                                  \
        if ((T) < 30) FSTAGE(JS, (T) + 2);                                              \
        short8 af[4], bf[4];                                                            \
        _Pragma("unroll") for (int mi = 0; mi < 4; mi++) af[mi] =                       \
            *(const short8*)&sA[JT][(wm * 64 + mi * 16 + lq) * 32 + rslot8];            \
        _Pragma("unroll") for (int ni = 0; ni < 4; ni++) bf[ni] =                       \
            *(const short8*)&sB[JT][(wn * 64 + ni * 16 + lq) * 32 + rslot8];            \
        __builtin_amdgcn_s_setprio(1);                                                  \
        _Pragma("unroll") for (int mi = 0; mi < 4; mi++)                                \
            _Pragma("unroll") for (int ni = 0; ni < 4; ni++) acc[mi][ni] =              \
                __builtin_amdgcn_mfma_f32_16x16x32_bf16(af[mi], bf[ni], acc[mi][ni],    \
                                                        0, 0, 0);                       \
        __builtin_amdgcn_s_setprio(0);                                                  \
    }

    FSTAGE(0, 0)
    FSTAGE(1, 1)
    FITER(0, 0, 2, 3)  FITER(1, 1, 0, 3)  FITER(2, 2, 1, 3)  FITER(3, 0, 2, 3)
    FITER(4, 1, 0, 3)  FITER(5, 2, 1, 3)  FITER(6, 0, 2, 3)  FITER(7, 1, 0, 3)
    FITER(8, 2, 1, 3)  FITER(9, 0, 2, 3)  FITER(10, 1, 0, 3) FITER(11, 2, 1, 3)
    FITER(12, 0, 2, 3) FITER(13, 1, 0, 3) FITER(14, 2, 1, 3) FITER(15, 0, 2, 3)
    FITER(16, 1, 0, 3) FITER(17, 2, 1, 3) FITER(18, 0, 2, 3) FITER(19, 1, 0, 3)
    FITER(20, 2, 1, 3) FITER(21, 0, 2, 3) FITER(22, 1, 0, 3) FITER(23, 2, 1, 3)
    FITER(24, 0, 2, 3) FITER(25, 1, 0, 3) FITER(26, 2, 1, 3) FITER(27, 0, 2, 3)
    FITER(28, 1, 0, 3) FITER(29, 2, 1, 3) FITER(30, 0, 2, 3) FITER(31, 1, 0, 0)
#undef FITER
#undef FSTAGE

    int col0 = n0 + wn * 64;
    int row0 = m0 + wm * 64;
#pragma unroll
    for (int mi = 0; mi < 4; mi++)
#pragma unroll
        for (int ni = 0; ni < 4; ni++) {
            int c = col0 + ni * 16 + lq;
            float bv = bias[c];
            int r = row0 + mi * 16 + lg * 4;
#pragma unroll
            for (int j = 0; j < 4; j++) {
                int idx = (r + j) * 512 + c;
                o[idx] = R[idx] + fmaxf(0.f, acc[mi][ni][j] + bv);
            }
        }
}

// ---------------- host ----------------
extern "C" void kernel_launch(void* const* d_in, const int* in_sizes, int n_in, void* d_out,
                              int out_size, void* d_ws, size_t ws_size, hipStream_t stream) {
    (void)in_sizes; (void)n_in; (void)out_size; (void)ws_size;
    char* ws = (char*)d_ws;
    unsigned short* Xb = (unsigned short*)(ws + OFF_XB);
    unsigned short* Yb = (unsigned short*)(ws + OFF_YB);
    unsigned short* WcatXT = (unsigned short*)(ws + OFF_WCXT);
    unsigned short* WcatYT = (unsigned short*)(ws + OFF_WCYT);
    unsigned short* WXT = (unsigned short*)(ws + OFF_WXT);
    unsigned short* WYT = (unsigned short*)(ws + OFF_WYT);
    float* biasX = (float*)(ws + OFF_BX);
    float* biasY = (float*)(ws + OFF_BY);
    unsigned short* PX = (unsigned short*)(ws + OFF_PX);
    unsigned short* PY = (unsigned short*)(ws + OFF_PY);
    unsigned short* VTxx = (unsigned short*)(ws + OFF_VT0);
    unsigned short* VTxy = (unsigned short*)(ws + OFF_VT1);
    unsigned short* VTyx = (unsigned short*)(ws + OFF_VT2);
    unsigned short* VTyy = (unsigned short*)(ws + OFF_VT3);
    unsigned short* Oxc = (unsigned short*)(ws + OFF_OX);
    unsigned short* Oyc = (unsigned short*)(ws + OFF_OY);

    // X-side cat order s=0..5: q_xx,k_xx,v_xx,q_xy,k_yx,v_yx
    // Y-side cat order s=0..5: k_xy,v_xy,q_yx,q_yy,k_yy,v_yy
    const int wiX[6] = {2, 4, 6, 8, 16, 18};
    const int wiY[6] = {10, 12, 14, 20, 22, 24};
    PackA pa;
    for (int i = 0; i < 6; i++) {
        pa.w[i] = (const float*)d_in[wiX[i]];
        pa.b[i] = (const float*)d_in[wiX[i] + 1];
        pa.w[6 + i] = (const float*)d_in[wiY[i]];
        pa.b[6 + i] = (const float*)d_in[wiY[i] + 1];
    }
    pa.wox = (const float*)d_in[26];
    pa.woy = (const float*)d_in[28];
    pa.X = (const float*)d_in[0];
    pa.Y = (const float*)d_in[1];

    k_pack<<<dim3(16, 32, 30), dim3(32, 8), 0, stream>>>(pa, WcatXT, WcatYT, biasX, biasY, WXT,
                                                         WYT, Xb, Yb);

    ProjArgs pr;
    pr.A[0] = Xb;        pr.A[1] = Yb;
    pr.BT[0] = WcatXT;   pr.BT[1] = WcatYT;
    pr.bias[0] = biasX;  pr.bias[1] = biasY;
    pr.C[0] = PX;        pr.C[1] = PY;
    pr.vtA[0] = VTxx;    pr.vtA[1] = VTxy;
    pr.svA[0] = 2;       pr.svA[1] = 1;
    pr.vtB[0] = VTyx;    pr.vtB[1] = VTyy;
    pr.svB[0] = 5;       pr.svB[1] = 5;
    k_proj<<<dim3(32, 24, 2), 512, 0, stream>>>(pr);

    k_attn<<<1024, 512, 0, stream>>>(PX, PY, VTxx, VTxy, VTyx, VTyy, Oxc, Oyc);

    k_final<<<dim3(32, 4, 2), 512, 0, stream>>>(Oxc, Oyc, WXT, WYT, (const float*)d_in[27],
                                                (const float*)d_in[29], (const float*)d_in[0],
                                                (const float*)d_in[1], (float*)d_out);
}